// Round 6
// baseline (512.092 us; speedup 1.0000x reference)
//
#include <hip/hip_runtime.h>

// CRF NLL on MI355X, round 6: branchless, pipelined single-wave scan.
//
// Wall time = 512 x per-step CRITICAL PATH (all 128 chains run concurrently;
// batching cannot help latency). Round-5 counters: VALU issue ~330 cyc/step
// vs 1171 total -> ~840 cyc stall from (a) a uniform branch per step,
// (b) exp(feat) on the path, (c) 16-deep dot chains, (d) DS turnaround.
// This round: (a) padded branchless body w/ write-redirect + masked S,
// (b) exp at prefetch time (4 steps early), (c) 16 chains 8-deep.
//
// Recurrence (probability domain, lagged rescale, proven r2-r5):
//   u_{t+1}[j] = exp(feat[t,j]) * (sum_i u_t[i] E[i][j]) / c_t,  S += log c_t

#define BB 128
#define TT 512
#define CC 128

#if __has_builtin(__builtin_amdgcn_fdot2_f32_bf16)
#define PATH_BF16 1
#endif

// ---- packed bf16 helpers (RNE pack; range ~ fp32) ----
__device__ __forceinline__ unsigned packp(float x, float y) {
    unsigned xu = __builtin_bit_cast(unsigned, x);
    unsigned yu = __builtin_bit_cast(unsigned, y);
    unsigned rx = (xu + 0x7fffu + ((xu >> 16) & 1u)) >> 16;          // RNE
    unsigned ry = (yu + 0x7fffu + ((yu >> 16) & 1u)) & 0xffff0000u;  // RNE
    return rx | ry;
}
__device__ __forceinline__ float lo2f(unsigned w) {
    return __builtin_bit_cast(float, w << 16);
}
__device__ __forceinline__ float hi2f(unsigned w) {
    return __builtin_bit_cast(float, w & 0xffff0000u);
}
#if defined(PATH_BF16)
typedef __bf16 bf2v __attribute__((ext_vector_type(2)));
__device__ __forceinline__ float dot2p(unsigned a, unsigned b, float c) {
    return __builtin_amdgcn_fdot2_f32_bf16(__builtin_bit_cast(bf2v, a),
                                           __builtin_bit_cast(bf2v, b), c, false);
}
#else
__device__ __forceinline__ float dot2p(unsigned a, unsigned b, float c) {
    return fmaf(hi2f(a), hi2f(b), fmaf(lo2f(a), lo2f(b), c));
}
#endif

__attribute__((amdgpu_waves_per_eu(1, 1)))
__global__ __launch_bounds__(64) void crf_wave(
    const float* __restrict__ feats,
    const int*   __restrict__ mask,
    const int*   __restrict__ tags,
    const float* __restrict__ trans,
    float*       __restrict__ acc)   // acc[0] += forward, acc[1] += gold score
{
    const int b    = blockIdx.x;
    const int lane = threadIdx.x;        // 0..63
    const int j0   = lane * 2;           // this lane's two state columns

    __shared__ __align__(16) unsigned ubuf[2][CC / 2];  // packed bf16 u, dbuf
    __shared__ unsigned udum[CC / 2];                   // padding-step sink

    const float* fb = feats + (size_t)b * TT * CC;

    // ================= len + gold score (off the scan path) ================
    int len = 0;
    {
        int tg[8], mk[8];
        #pragma unroll
        for (int k = 0; k < 8; ++k) {
            const int t = k * 64 + lane;
            mk[k] = mask[b * TT + t];
            tg[k] = tags[b * TT + t];
        }
        #pragma unroll
        for (int k = 0; k < 8; ++k) len += __popcll(__ballot(mk[k]));

        float sc = 0.0f;
        #pragma unroll
        for (int k = 0; k < 8; ++k) {
            const int t   = k * 64 + lane;
            const int up  = __shfl_up(tg[k], 1);
            const int lst = (k > 0) ? __shfl(tg[k - 1], 63) : (CC - 2);
            const int pv  = (lane == 0) ? lst : up;
            if (mk[k]) {
                sc += fb[(size_t)t * CC + tg[k]];       // emission
                sc += trans[pv * CC + tg[k]];           // transition into t
            }
            if (t == len - 1) sc += trans[tg[k] * CC + (CC - 1)];   // -> STOP
        }
        #pragma unroll
        for (int o = 1; o <= 32; o <<= 1) sc += __shfl_xor(sc, o);
        if (lane == 0) atomicAdd(&acc[1], sc);
    }

    // ===== E fragments: packed bf16 pairs of exp(trans), 128 regs ==========
    // E0[p] = pack(E[2p][j0],   E[2p+1][j0]); E1 likewise for column j0+1.
    unsigned E0[64], E1[64];
    #pragma unroll
    for (int p = 0; p < 64; ++p) {
        const float2 ta = *(const float2*)&trans[(size_t)(2 * p)     * CC + j0];
        const float2 tb = *(const float2*)&trans[(size_t)(2 * p + 1) * CC + j0];
        E0[p] = packp(__expf(ta.x), __expf(tb.x));
        E1[p] = packp(__expf(ta.y), __expf(tb.y));
    }
    const float Es0 = __expf(trans[(size_t)j0       * CC + (CC - 1)]);
    const float Es1 = __expf(trans[(size_t)(j0 + 1) * CC + (CC - 1)]);

    // ================= seed u_1 = exp(feat[0]) * E[START][:] ===============
    {
        const float2 f0 = *(const float2*)&fb[j0];
        const float tEx = __expf(trans[(size_t)(CC - 2) * CC + j0]);
        const float tEy = __expf(trans[(size_t)(CC - 2) * CC + j0 + 1]);
        ubuf[0][lane] = packp(__expf(f0.x) * tEx, __expf(f0.y) * tEy);
    }

    // ===== prefetch feats rows 1..4 AND pre-exponentiate (off the path) ====
    float2 fx[4];
    float  ex0[4], ex1[4];
    #pragma unroll
    for (int k = 0; k < 4; ++k) {
        int tn = 1 + k; tn = (tn < TT) ? tn : (TT - 1);
        fx[k]  = *(const float2*)&fb[(size_t)tn * CC + j0];
        ex0[k] = __expf(fx[k].x);
        ex1[k] = __expf(fx[k].y);
    }

    // ========== scan t = 1..len-1, padded to x4, branchless body ==========
    // step t: reads u_t from ubuf[(t+1)&1] = ubuf[k&1]  (t = tb+k, tb odd)
    //         writes u_{t+1} to ubuf[t&1]  = ubuf[(k+1)&1], or udum if pad
    float S = 0.0f;
    for (int tb = 1; tb < len; tb += 4) {
        #pragma unroll
        for (int k = 0; k < 4; ++k) {
            const int t = tb + k;
            const uint4* q = (const uint4*)&ubuf[k & 1][0];

            float A[8], Bc[8];
            #pragma unroll
            for (int h = 0; h < 8; ++h) { A[h] = 0.0f; Bc[h] = 0.0f; }
            float cs = 1.0f;
            #pragma unroll
            for (int kq = 0; kq < 16; ++kq) {
                const uint4 P = q[kq];               // broadcast ds_read_b128
                if (kq == 0) cs = lo2f(P.x);         // c = u_t[0]
                const int p = kq * 4, h = (kq & 1) * 4;
                A[h + 0]  = dot2p(E0[p + 0], P.x, A[h + 0]);
                A[h + 1]  = dot2p(E0[p + 1], P.y, A[h + 1]);
                A[h + 2]  = dot2p(E0[p + 2], P.z, A[h + 2]);
                A[h + 3]  = dot2p(E0[p + 3], P.w, A[h + 3]);
                Bc[h + 0] = dot2p(E1[p + 0], P.x, Bc[h + 0]);
                Bc[h + 1] = dot2p(E1[p + 1], P.y, Bc[h + 1]);
                Bc[h + 2] = dot2p(E1[p + 2], P.z, Bc[h + 2]);
                Bc[h + 3] = dot2p(E1[p + 3], P.w, Bc[h + 3]);
            }
            const float s0 = ((A[0] + A[1]) + (A[2] + A[3]))
                           + ((A[4] + A[5]) + (A[6] + A[7]));
            const float s1 = ((Bc[0] + Bc[1]) + (Bc[2] + Bc[3]))
                           + ((Bc[4] + Bc[5]) + (Bc[6] + Bc[7]));

            const float ri = __builtin_amdgcn_rcpf(cs);
            const float vx = ex0[k] * s0 * ri;       // ex precomputed 4 steps
            const float vy = ex1[k] * s1 * ri;       // ago -> off the path

            // masked S accumulate (branchless; cs finite+positive always)
            const float flg = (t < len) ? 1.0f : 0.0f;
            S = fmaf(flg, __logf(cs), S);

            // prefetch feats row t+4 + pre-exp (consumed 4 steps later)
            int tn = t + 4; tn = (tn < TT) ? tn : (TT - 1);
            fx[k]  = *(const float2*)&fb[(size_t)tn * CC + j0];
            ex0[k] = __expf(fx[k].x);
            ex1[k] = __expf(fx[k].y);

            // write u_{t+1}; padding steps land in the dummy row (no branch)
            unsigned* wp = (t < len) ? &ubuf[(k + 1) & 1][lane] : &udum[lane];
            *wp = packp(vx, vy);
        }
    }

    // ======= terminal: log sum_j u_len[j] * exp(trans[j][STOP]) + S ========
    const unsigned uw = ubuf[(len - 1) & 1][lane];
    float z = lo2f(uw) * Es0 + hi2f(uw) * Es1;
    #pragma unroll
    for (int o = 1; o <= 32; o <<= 1) z += __shfl_xor(z, o);
    if (lane == 0) atomicAdd(&acc[0], __logf(z) + S);
}

__global__ void crf_final(const float* __restrict__ acc, float* __restrict__ out)
{
    out[0] = (acc[0] - acc[1]) * (1.0f / (float)BB);
}

extern "C" void kernel_launch(void* const* d_in, const int* in_sizes, int n_in,
                              void* d_out, int out_size, void* d_ws, size_t ws_size,
                              hipStream_t stream)
{
    const float* feats = (const float*)d_in[0];
    const int*   mask  = (const int*)d_in[1];
    const int*   tags  = (const int*)d_in[2];
    const float* trans = (const float*)d_in[3];
    float* out = (float*)d_out;
    float* acc = (float*)d_ws;

    hipMemsetAsync(acc, 0, 2 * sizeof(float), stream);
    crf_wave<<<BB, 64, 0, stream>>>(feats, mask, tags, trans, acc);
    crf_final<<<1, 1, 0, stream>>>(acc, out);
}

// Round 7
// 313.838 us; speedup vs baseline: 1.6317x; 1.6317x over previous
//
#include <hip/hip_runtime.h>

// CRF NLL on MI355X, round 7: register-only scan — NO LDS in the loop.
//
// r6 post-mortem: exp placed right after its own prefetch load = per-step
// vmcnt wait on a fresh load (~600 cyc) -> 2x regression. Reverted to r5's
// consume-then-reload order.
// r5 stall analysis: the per-step LDS round trip (ds_write -> 16 broadcast
// ds_read_b128, ~300+ cyc serialized) dominates. The u vector is 64 packed
// words -> broadcast it with v_readlane_b32 into SGPRs instead (VALU op,
// no memory), and feed v_dot2_f32_bf16 whose src0 may be an SGPR.
// Per-step: pack -> 64 readlane -> 128 dot2 -> reduce/rescale. Issue-bound
// ~430 cyc/step.
//
// Recurrence (probability domain, lagged rescale by c=u[0], proven r2-r6):
//   u_{t+1}[j] = exp(feat[t,j]) * (sum_i u_t[i] E[i][j]) / c_t,  S += log c_t

#define BB 128
#define TT 512
#define CC 128

#if __has_builtin(__builtin_amdgcn_fdot2_f32_bf16)
#define PATH_BF16 1
#endif

// ---- packed bf16 helpers (RNE pack; bf16 exponent range == fp32) ----
__device__ __forceinline__ unsigned packp(float x, float y) {
    unsigned xu = __builtin_bit_cast(unsigned, x);
    unsigned yu = __builtin_bit_cast(unsigned, y);
    unsigned rx = (xu + 0x7fffu + ((xu >> 16) & 1u)) >> 16;          // RNE
    unsigned ry = (yu + 0x7fffu + ((yu >> 16) & 1u)) & 0xffff0000u;  // RNE
    return rx | ry;
}
__device__ __forceinline__ float lo2f(unsigned w) {
    return __builtin_bit_cast(float, w << 16);
}
__device__ __forceinline__ float hi2f(unsigned w) {
    return __builtin_bit_cast(float, w & 0xffff0000u);
}
#if defined(PATH_BF16)
typedef __bf16 bf2v __attribute__((ext_vector_type(2)));
__device__ __forceinline__ float dot2p(unsigned a, unsigned b, float c) {
    return __builtin_amdgcn_fdot2_f32_bf16(__builtin_bit_cast(bf2v, a),
                                           __builtin_bit_cast(bf2v, b), c, false);
}
#else
__device__ __forceinline__ float dot2p(unsigned a, unsigned b, float c) {
    return fmaf(hi2f(a), hi2f(b), fmaf(lo2f(a), lo2f(b), c));
}
#endif

__attribute__((amdgpu_waves_per_eu(1, 1)))
__global__ __launch_bounds__(64) void crf_wave(
    const float* __restrict__ feats,
    const int*   __restrict__ mask,
    const int*   __restrict__ tags,
    const float* __restrict__ trans,
    float*       __restrict__ acc)   // acc[0] += forward, acc[1] += gold score
{
    const int b    = blockIdx.x;
    const int lane = threadIdx.x;        // 0..63
    const int j0   = lane * 2;           // this lane's two state columns

    const float* fb = feats + (size_t)b * TT * CC;

    // ================= len + gold score (off the scan path) ================
    int len = 0;
    {
        int tg[8], mk[8];
        #pragma unroll
        for (int k = 0; k < 8; ++k) {
            const int t = k * 64 + lane;
            mk[k] = mask[b * TT + t];
            tg[k] = tags[b * TT + t];
        }
        #pragma unroll
        for (int k = 0; k < 8; ++k) len += __popcll(__ballot(mk[k]));

        float sc = 0.0f;
        #pragma unroll
        for (int k = 0; k < 8; ++k) {
            const int t   = k * 64 + lane;
            const int up  = __shfl_up(tg[k], 1);
            const int lst = (k > 0) ? __shfl(tg[k - 1], 63) : (CC - 2);
            const int pv  = (lane == 0) ? lst : up;
            if (mk[k]) {
                sc += fb[(size_t)t * CC + tg[k]];       // emission
                sc += trans[pv * CC + tg[k]];           // transition into t
            }
            if (t == len - 1) sc += trans[tg[k] * CC + (CC - 1)];   // -> STOP
        }
        #pragma unroll
        for (int o = 1; o <= 32; o <<= 1) sc += __shfl_xor(sc, o);
        if (lane == 0) atomicAdd(&acc[1], sc);
    }

    // ===== E fragments: packed bf16 pairs of exp(trans), 128 regs ==========
    // E0[p] = pack(E[2p][j0],   E[2p+1][j0]); E1 likewise for column j0+1.
    unsigned E0[64], E1[64];
    #pragma unroll
    for (int p = 0; p < 64; ++p) {
        const float2 ta = *(const float2*)&trans[(size_t)(2 * p)     * CC + j0];
        const float2 tb = *(const float2*)&trans[(size_t)(2 * p + 1) * CC + j0];
        E0[p] = packp(__expf(ta.x), __expf(tb.x));
        E1[p] = packp(__expf(ta.y), __expf(tb.y));
    }
    const float Es0 = __expf(trans[(size_t)j0       * CC + (CC - 1)]);
    const float Es1 = __expf(trans[(size_t)(j0 + 1) * CC + (CC - 1)]);

    // ================= seed u_1 = exp(feat[0]) * E[START][:] ===============
    unsigned uw;                          // this lane's packed u pair (STATE)
    {
        const float2 f0 = *(const float2*)&fb[j0];
        const float tEx = __expf(trans[(size_t)(CC - 2) * CC + j0]);
        const float tEy = __expf(trans[(size_t)(CC - 2) * CC + j0 + 1]);
        uw = packp(__expf(f0.x) * tEx, __expf(f0.y) * tEy);
    }

    // feats prefetch, 4 deep (consume old data FIRST, then reload — r6 bug fix)
    float2 fx[4];
    #pragma unroll
    for (int k = 0; k < 4; ++k) {
        int tn = 1 + k; tn = (tn < TT) ? tn : (TT - 1);
        fx[k] = *(const float2*)&fb[(size_t)tn * CC + j0];
    }

    // ================= scan t = 1 .. len-1, register-only ==================
    float S = 0.0f;
    for (int tb = 1; tb < len; tb += 4) {
        #pragma unroll
        for (int k = 0; k < 4; ++k) {
            const int t = tb + k;
            if (t < len) {                               // wave-uniform
                // broadcast the whole u vector into SGPRs (VALU, no memory)
                unsigned su[64];
                #pragma unroll
                for (int p = 0; p < 64; ++p)
                    su[p] = __builtin_amdgcn_readlane(uw, p);

                float A[8], Bc[8];
                #pragma unroll
                for (int h = 0; h < 8; ++h) { A[h] = 0.0f; Bc[h] = 0.0f; }
                #pragma unroll
                for (int p = 0; p < 64; ++p) {
                    const int h = p & 7;                 // 8 chains, 8-deep
                    A[h]  = dot2p(E0[p], su[p], A[h]);
                    Bc[h] = dot2p(E1[p], su[p], Bc[h]);
                }
                const float s0 = ((A[0] + A[1]) + (A[2] + A[3]))
                               + ((A[4] + A[5]) + (A[6] + A[7]));
                const float s1 = ((Bc[0] + Bc[1]) + (Bc[2] + Bc[3]))
                               + ((Bc[4] + Bc[5]) + (Bc[6] + Bc[7]));

                const float cs = lo2f(su[0]);            // c = u_t[0]
                const float ri = __builtin_amdgcn_rcpf(cs);
                const float e0 = __expf(fx[k].x);        // data loaded 4 steps ago
                const float e1 = __expf(fx[k].y);
                S += __logf(cs);

                // reload AFTER consumption (r6 bug: reload-then-exp stalled)
                int tn = t + 4; tn = (tn < TT) ? tn : (TT - 1);
                fx[k] = *(const float2*)&fb[(size_t)tn * CC + j0];

                uw = packp(e0 * s0 * ri, e1 * s1 * ri);  // u_{t+1}
            }
        }
    }

    // ======= terminal: log sum_j u_len[j] * exp(trans[j][STOP]) + S ========
    float z = lo2f(uw) * Es0 + hi2f(uw) * Es1;
    #pragma unroll
    for (int o = 1; o <= 32; o <<= 1) z += __shfl_xor(z, o);
    if (lane == 0) atomicAdd(&acc[0], __logf(z) + S);
}

__global__ void crf_final(const float* __restrict__ acc, float* __restrict__ out)
{
    out[0] = (acc[0] - acc[1]) * (1.0f / (float)BB);
}

extern "C" void kernel_launch(void* const* d_in, const int* in_sizes, int n_in,
                              void* d_out, int out_size, void* d_ws, size_t ws_size,
                              hipStream_t stream)
{
    const float* feats = (const float*)d_in[0];
    const int*   mask  = (const int*)d_in[1];
    const int*   tags  = (const int*)d_in[2];
    const float* trans = (const float*)d_in[3];
    float* out = (float*)d_out;
    float* acc = (float*)d_ws;

    hipMemsetAsync(acc, 0, 2 * sizeof(float), stream);
    crf_wave<<<BB, 64, 0, stream>>>(feats, mask, tags, trans, acc);
    crf_final<<<1, 1, 0, stream>>>(acc, out);
}